// Round 16
// baseline (120.702 us; speedup 1.0000x reference)
//
#include <hip/hip_runtime.h>
#include <hip/hip_bf16.h>
#include <math.h>

#define B_    16384
#define F_    26
#define E_    32
#define L_    50
#define CT_   13
#define D0_   909
#define KP    960                          // K padded to 15*64
#define D1_   512
#define D2_   256

#define NEMB  4096                         // embed blocks (4 samples each)
#define W2N   (D1_ * KP)                   // 491520
#define W3N   (D2_ * D1_)                  // 131072
#define CVTB  ((W2N + W3N + 255) / 256)    // 2432

typedef __bf16 bf16x8 __attribute__((ext_vector_type(8)));
typedef float f32x4 __attribute__((ext_vector_type(4)));

__device__ inline unsigned short f2b(float f) {
    union { __hip_bfloat16 h; unsigned short u; } v;
    v.h = __float2bfloat16(f);
    return v.u;
}
__device__ inline void gld_lds16(const void* g, void* l) {
    __builtin_amdgcn_global_load_lds(
        (const __attribute__((address_space(1))) unsigned int*)g,
        (__attribute__((address_space(3))) unsigned int*)l, 16, 0, 0);
}

// ================= D0: embed (blocks 0..4095) + weight-cvt (blocks 4096..) =================
__global__ __launch_bounds__(256) void embed_cvt_kernel(
    const int* __restrict__ oi, const float* __restrict__ ox,
    const int* __restrict__ i1, const float* __restrict__ x1,
    const int* __restrict__ i2, const float* __restrict__ x2,
    const float* __restrict__ ct, const float* __restrict__ wtab,
    const float* __restrict__ dtab,
    const float* __restrict__ w2, const float* __restrict__ w3,
    __hip_bfloat16* __restrict__ x0b, float* __restrict__ wid,
    __hip_bfloat16* __restrict__ w2b, __hip_bfloat16* __restrict__ w3b)
{
    const int tid  = threadIdx.x;
    const int lane = tid & 63;
    const int w    = tid >> 6;

    if (blockIdx.x >= NEMB) {
        // ---- weight conversion: fp32 -> bf16, W2 K-padded to 960 ----
        int i = (blockIdx.x - NEMB) * 256 + tid;
        if (i < W2N) {
            int r = i / KP, c = i - r * KP;
            float v = (c < D0_) ? w2[r * D0_ + c] : 0.f;
            w2b[i] = __float2bfloat16(v);
        } else {
            int j = i - W2N;
            if (j < W3N) w3b[j] = __float2bfloat16(w3[j]);
        }
        return;
    }

    // ---- embed: 4 samples per block (R6-verified; row stride KP) ----
    const int s = blockIdx.x * 4 + w;
    const int g = lane >> 3;
    const int l = lane & 7;
    unsigned short* xrow = (unsigned short*)(x0b + (size_t)s * KP);
    const f32x4* dt4 = (const f32x4*)dtab;

    int koh[4]; float soh[4];
#pragma unroll
    for (int t = 0; t < 4; t++) {
        int f = g + 8 * t; bool v = (f < F_);
        koh[t] = v ? oi[s * F_ + f] : 0;
        soh[t] = v ? ox[s * F_ + f] : 0.f;
    }
    int k1[7], k2[7]; float sc1[7], sc2[7];
#pragma unroll
    for (int t = 0; t < 7; t++) {
        int j = g + 8 * t; bool v = (j < L_);
        k1[t]  = v ? i1[s * L_ + j] : 0;
        sc1[t] = v ? x1[s * L_ + j] : 0.f;
        k2[t]  = v ? i2[s * L_ + j] : 0;
        sc2[t] = v ? x2[s * L_ + j] : 0.f;
    }
    f32x4 r1[7], r2[7], roh[4];
#pragma unroll
    for (int t = 0; t < 7; t++) r1[t] = dt4[(size_t)k1[t] * 8 + l];
#pragma unroll
    for (int t = 0; t < 7; t++) r2[t] = dt4[(size_t)k2[t] * 8 + l];
#pragma unroll
    for (int t = 0; t < 4; t++) roh[t] = dt4[(size_t)koh[t] * 8 + l];

#pragma unroll
    for (int t = 0; t < 4; t++) {
        int f = g + 8 * t;
        if (f < F_) {
            ushort4 o;
            o.x = f2b(roh[t].x * soh[t]); o.y = f2b(roh[t].y * soh[t]);
            o.z = f2b(roh[t].z * soh[t]); o.w = f2b(roh[t].w * soh[t]);
            *(ushort4*)(xrow + f * E_ + l * 4) = o;
        }
    }
    f32x4 a1 = {0.f,0.f,0.f,0.f}, a2 = {0.f,0.f,0.f,0.f};
#pragma unroll
    for (int t = 0; t < 7; t++) {
        a1.x = fmaf(r1[t].x, sc1[t], a1.x); a1.y = fmaf(r1[t].y, sc1[t], a1.y);
        a1.z = fmaf(r1[t].z, sc1[t], a1.z); a1.w = fmaf(r1[t].w, sc1[t], a1.w);
        a2.x = fmaf(r2[t].x, sc2[t], a2.x); a2.y = fmaf(r2[t].y, sc2[t], a2.y);
        a2.z = fmaf(r2[t].z, sc2[t], a2.z); a2.w = fmaf(r2[t].w, sc2[t], a2.w);
    }
#pragma unroll
    for (int m = 8; m < 64; m <<= 1) {
        a1.x += __shfl_xor(a1.x, m); a1.y += __shfl_xor(a1.y, m);
        a1.z += __shfl_xor(a1.z, m); a1.w += __shfl_xor(a1.w, m);
        a2.x += __shfl_xor(a2.x, m); a2.y += __shfl_xor(a2.y, m);
        a2.z += __shfl_xor(a2.z, m); a2.w += __shfl_xor(a2.w, m);
    }
    if (g == 0) {
        ushort4 o; o.x = f2b(a1.x); o.y = f2b(a1.y); o.z = f2b(a1.z); o.w = f2b(a1.w);
        *(ushort4*)(xrow + F_ * E_ + l * 4) = o;
    }
    if (g == 1) {
        ushort4 o; o.x = f2b(a2.x); o.y = f2b(a2.y); o.z = f2b(a2.z); o.w = f2b(a2.w);
        *(ushort4*)(xrow + F_ * E_ + E_ + l * 4) = o;
    }
    // ctns (cols 896..908) + explicit zero through col 959
    {
        float v = (lane < CT_) ? ct[s * CT_ + lane] : 0.f;
        xrow[F_ * E_ + 2 * E_ + lane] = f2b(v);
    }
    float acc = 0.f;
#pragma unroll
    for (int t = lane; t < F_ + 2 * L_; t += 64) {
        int idx; float xv;
        if (t < F_)            { idx = oi[s * F_ + t];           xv = ox[s * F_ + t]; }
        else if (t < F_ + L_)  { int j = t - F_;      idx = i1[s * L_ + j]; xv = x1[s * L_ + j]; }
        else                   { int j = t - F_ - L_; idx = i2[s * L_ + j]; xv = x2[s * L_ + j]; }
        acc += wtab[idx] * xv;
    }
    for (int o = 32; o; o >>= 1) acc += __shfl_xor(acc, o);
    if (lane == 0) wid[s] = (float)E_ * acc;
}

// ================= D1: fused MLP — 64 rows/block, BN=512 full width, h1 in LDS =================
// G1: h1(64x512) = leaky(x0(64x960) @ W2^T + b2)      (15 K-steps of 64, 32 MFMA/wave/step)
// G2: h2(64x256) = leaky(h1 @ W3^T + b3)               (8 K-steps of 64, h1 read from LDS)
// F : out = sigmoid(h2 . w4 + b4 + wide)
__global__ __launch_bounds__(512) void mlp_kernel(
    const __hip_bfloat16* __restrict__ x0b,
    const __hip_bfloat16* __restrict__ w2b, const float* __restrict__ b2,
    const __hip_bfloat16* __restrict__ w3b, const float* __restrict__ b3,
    const float* __restrict__ w4, const float* __restrict__ b4,
    const float* __restrict__ wid, float* __restrict__ out)
{
    __shared__ __align__(16) __hip_bfloat16 As[2][64 * 32];      //  8 KB (x0 K-planes)
    __shared__ __align__(16) __hip_bfloat16 Bs[2][512 * 32];     // 64 KB (W2 strip; W3 reuses)
    __shared__ __align__(16) unsigned short h1s[16][64 * 32];    // 64 KB (h1, 32-col chunks)
    __shared__ float parts[512];                                 //  2 KB

    const int tid  = threadIdx.x;
    const int lane = tid & 63;
    const int w    = tid >> 6;           // wave 0..7
    const int r0   = blockIdx.x * 64;
    const int fr   = lane & 15;
    const int kq   = lane >> 4;          // 0..3
    const int kg   = kq * 8;
    const int srow = lane >> 2;          // 0..15
    const int scol = (lane & 3) * 8;

    // ---------------- G1: 15 K-steps of 64 ----------------
    f32x4 acc[4][4] = {};
    for (int k0 = 0; k0 < KP; k0 += 64) {
        // A: wave w stages plane w>>2, rows (w&3)*16 .. +15  (1 gld/wave)
        {
            const int p = w >> 2;
            const int rbase = (w & 3) * 16;
            gld_lds16(x0b + (size_t)(r0 + rbase + srow) * KP + k0 + p * 32 + scol,
                      (char*)As + p * 4096 + rbase * 64);
        }
        // B: wave w stages rows w*64..w*64+63 of both planes (8 gld/wave)
#pragma unroll
        for (int p = 0; p < 2; p++)
#pragma unroll
            for (int rr = 0; rr < 4; rr++)
                gld_lds16(w2b + (size_t)(w * 64 + rr * 16 + srow) * KP + k0 + p * 32 + scol,
                          (char*)Bs + p * 32768 + (w * 64 + rr * 16) * 64);
        __syncthreads();

#pragma unroll
        for (int p = 0; p < 2; p++) {
            bf16x8 af[4], bfv[4];
#pragma unroll
            for (int i = 0; i < 4; i++)
                af[i] = *(const bf16x8*)(As[p] + (i * 16 + fr) * 32 + kg);
#pragma unroll
            for (int j = 0; j < 4; j++)
                bfv[j] = *(const bf16x8*)(Bs[p] + (w * 64 + j * 16 + fr) * 32 + kg);
#pragma unroll
            for (int i = 0; i < 4; i++)
#pragma unroll
                for (int j = 0; j < 4; j++)
                    acc[i][j] = __builtin_amdgcn_mfma_f32_16x16x32_bf16(af[i], bfv[j], acc[i][j], 0, 0, 0);
        }
        __syncthreads();
    }

    // ---- h1 -> LDS (bias + leaky); chunk c holds cols c*32..c*32+31, row-major 64B rows ----
#pragma unroll
    for (int j = 0; j < 4; j++) {
        const int n  = w * 64 + j * 16 + fr;        // output col 0..511
        const float bb = b2[n];
        const int chunk = n >> 5;
        const int kk    = n & 31;
#pragma unroll
        for (int i = 0; i < 4; i++)
#pragma unroll
            for (int r = 0; r < 4; r++) {
                const int row = i * 16 + kq * 4 + r;
                float v = acc[i][j][r] + bb;
                v = (v >= 0.f) ? v : 0.01f * v;
                h1s[chunk][row * 32 + kk] = f2b(v);
            }
    }
    __syncthreads();

    // ---------------- G2: 8 K-steps of 64 (A from h1s chunks 2q, 2q+1) ----------------
    f32x4 acc2[4][2] = {};
    for (int q = 0; q < 8; q++) {
        // stage W3 rows (output cols) w*32..w*32+31, both planes (4 gld/wave)
#pragma unroll
        for (int p = 0; p < 2; p++)
#pragma unroll
            for (int rr = 0; rr < 2; rr++)
                gld_lds16(w3b + (size_t)(w * 32 + rr * 16 + srow) * D1_ + q * 64 + p * 32 + scol,
                          (char*)Bs + p * 16384 + (w * 32 + rr * 16) * 64);
        __syncthreads();

#pragma unroll
        for (int p = 0; p < 2; p++) {
            const __hip_bfloat16* Bp = (const __hip_bfloat16*)((char*)Bs + p * 16384);
            bf16x8 af[4], bfv[2];
#pragma unroll
            for (int i = 0; i < 4; i++)
                af[i] = *(const bf16x8*)(&h1s[2 * q + p][(i * 16 + fr) * 32 + kg]);
#pragma unroll
            for (int j = 0; j < 2; j++)
                bfv[j] = *(const bf16x8*)(Bp + (w * 32 + j * 16 + fr) * 32 + kg);
#pragma unroll
            for (int i = 0; i < 4; i++)
#pragma unroll
                for (int j = 0; j < 2; j++)
                    acc2[i][j] = __builtin_amdgcn_mfma_f32_16x16x32_bf16(af[i], bfv[j], acc2[i][j], 0, 0, 0);
        }
        __syncthreads();
    }

    // ---------------- F: bias+leaky, dot w4 over this wave's 32 cols, reduce, sigmoid ----------------
    float p4[4][4];
#pragma unroll
    for (int i = 0; i < 4; i++)
#pragma unroll
        for (int r = 0; r < 4; r++) p4[i][r] = 0.f;
#pragma unroll
    for (int j = 0; j < 2; j++) {
        const int n = w * 32 + j * 16 + fr;
        const float bb = b3[n];
        const float wv = w4[n];
#pragma unroll
        for (int i = 0; i < 4; i++)
#pragma unroll
            for (int r = 0; r < 4; r++) {
                float v = acc2[i][j][r] + bb;
                v = (v >= 0.f) ? v : 0.01f * v;
                p4[i][r] = fmaf(v, wv, p4[i][r]);
            }
    }
#pragma unroll
    for (int m = 1; m < 16; m <<= 1)
#pragma unroll
        for (int i = 0; i < 4; i++)
#pragma unroll
            for (int r = 0; r < 4; r++) p4[i][r] += __shfl_xor(p4[i][r], m);
    if (fr == 0) {
#pragma unroll
        for (int i = 0; i < 4; i++)
#pragma unroll
            for (int r = 0; r < 4; r++)
                parts[w * 64 + i * 16 + kq * 4 + r] = p4[i][r];
    }
    __syncthreads();
    if (tid < 64) {
        float x = b4[0] + wid[r0 + tid];
#pragma unroll
        for (int ww = 0; ww < 8; ww++) x += parts[ww * 64 + tid];
        out[r0 + tid] = 1.f / (1.f + expf(-x));
    }
}

extern "C" void kernel_launch(void* const* d_in, const int* in_sizes, int n_in,
                              void* d_out, int out_size, void* d_ws, size_t ws_size,
                              hipStream_t stream) {
    const int*   oi  = (const int*)  d_in[0];
    const float* ox  = (const float*)d_in[1];
    const int*   i1  = (const int*)  d_in[2];
    const float* x1  = (const float*)d_in[3];
    const int*   i2  = (const int*)  d_in[4];
    const float* x2  = (const float*)d_in[5];
    const float* ct  = (const float*)d_in[6];
    const float* wt  = (const float*)d_in[7];
    const float* dt  = (const float*)d_in[8];
    const float* w2  = (const float*)d_in[9];
    const float* b2  = (const float*)d_in[10];
    const float* w3  = (const float*)d_in[11];
    const float* b3  = (const float*)d_in[12];
    const float* w4  = (const float*)d_in[13];
    const float* b4  = (const float*)d_in[14];
    float* out = (float*)d_out;

    char* ws = (char*)d_ws;
    __hip_bfloat16* x0b = (__hip_bfloat16*)(ws);                    // 16384*960*2  = 31,457,280
    float*          wid = (float*)         (ws + 31457280);         // 16384*4      =     65,536
    __hip_bfloat16* w2b = (__hip_bfloat16*)(ws + 31522816);         // 491520*2     =    983,040
    __hip_bfloat16* w3b = (__hip_bfloat16*)(ws + 32505856);         // 131072*2     =    262,144

    embed_cvt_kernel<<<NEMB + CVTB, 256, 0, stream>>>(
        oi, ox, i1, x1, i2, x2, ct, wt, dt, w2, w3, x0b, wid, w2b, w3b);
    mlp_kernel<<<B_ / 64, 512, 0, stream>>>(x0b, w2b, b2, w3b, b3, w4, b4, wid, out);
}

// Round 17
// 113.538 us; speedup vs baseline: 1.0631x; 1.0631x over previous
//
#include <hip/hip_runtime.h>
#include <hip/hip_bf16.h>
#include <math.h>

#define B_    16384
#define F_    26
#define E_    32
#define L_    50
#define CT_   13
#define D0_   909
#define KP    960                          // K padded to 15*64
#define D1_   512
#define D2_   256

#define NEMB  4096                         // embed blocks (4 samples each)
#define W2N   (D1_ * KP)                   // 491520
#define W3N   (D2_ * D1_)                  // 131072
#define CVTB  ((W2N + W3N + 255) / 256)    // 2432

typedef __bf16 bf16x8 __attribute__((ext_vector_type(8)));
typedef float f32x4 __attribute__((ext_vector_type(4)));

__device__ inline unsigned short f2b(float f) {
    union { __hip_bfloat16 h; unsigned short u; } v;
    v.h = __float2bfloat16(f);
    return v.u;
}
__device__ inline void gld_lds16(const void* g, void* l) {
    __builtin_amdgcn_global_load_lds(
        (const __attribute__((address_space(1))) unsigned int*)g,
        (__attribute__((address_space(3))) unsigned int*)l, 16, 0, 0);
}

// ================= D0: embed (blocks 0..4095) + weight-cvt (blocks 4096..) =================
// Inputs (indices/scales/ctns) are nontemporal first-touch loads: they are pure
// streams (139MB/iter) and evicting them first keeps the 128MB deep table
// L3-resident across timed replays. Table/x0/weights stay normal-cached.
// Wide part is recomputed from the preloaded registers (no input re-reads).
__global__ __launch_bounds__(256) void embed_cvt_kernel(
    const int* __restrict__ oi, const float* __restrict__ ox,
    const int* __restrict__ i1, const float* __restrict__ x1,
    const int* __restrict__ i2, const float* __restrict__ x2,
    const float* __restrict__ ct, const float* __restrict__ wtab,
    const float* __restrict__ dtab,
    const float* __restrict__ w2, const float* __restrict__ w3,
    __hip_bfloat16* __restrict__ x0b, float* __restrict__ wid,
    __hip_bfloat16* __restrict__ w2b, __hip_bfloat16* __restrict__ w3b)
{
    const int tid  = threadIdx.x;
    const int lane = tid & 63;
    const int w    = tid >> 6;

    if (blockIdx.x >= NEMB) {
        // ---- weight conversion: fp32 -> bf16, W2 K-padded to 960 ----
        int i = (blockIdx.x - NEMB) * 256 + tid;
        if (i < W2N) {
            int r = i / KP, c = i - r * KP;
            float v = (c < D0_) ? w2[r * D0_ + c] : 0.f;
            w2b[i] = __float2bfloat16(v);
        } else {
            int j = i - W2N;
            if (j < W3N) w3b[j] = __float2bfloat16(w3[j]);
        }
        return;
    }

    // ---- embed: 4 samples per block (row stride KP) ----
    const int s = blockIdx.x * 4 + w;
    const int g = lane >> 3;     // group 0..7
    const int l = lane & 7;      // lane-in-group
    unsigned short* xrow = (unsigned short*)(x0b + (size_t)s * KP);
    const f32x4* dt4 = (const f32x4*)dtab;

    // preload all indices & scales (branchless; masked -> idx 0, scale 0) [nt]
    int koh[4]; float soh[4];
#pragma unroll
    for (int t = 0; t < 4; t++) {
        int f = g + 8 * t; bool v = (f < F_);
        koh[t] = v ? __builtin_nontemporal_load(oi + s * F_ + f) : 0;
        soh[t] = v ? __builtin_nontemporal_load(ox + s * F_ + f) : 0.f;
    }
    int k1[7], k2[7]; float sc1[7], sc2[7];
#pragma unroll
    for (int t = 0; t < 7; t++) {
        int j = g + 8 * t; bool v = (j < L_);
        k1[t]  = v ? __builtin_nontemporal_load(i1 + s * L_ + j) : 0;
        sc1[t] = v ? __builtin_nontemporal_load(x1 + s * L_ + j) : 0.f;
        k2[t]  = v ? __builtin_nontemporal_load(i2 + s * L_ + j) : 0;
        sc2[t] = v ? __builtin_nontemporal_load(x2 + s * L_ + j) : 0.f;
    }

    // issue all 18 row gathers (normal-cached; table should be L3-resident)
    f32x4 r1[7], r2[7], roh[4];
#pragma unroll
    for (int t = 0; t < 7; t++) r1[t] = dt4[(size_t)k1[t] * 8 + l];
#pragma unroll
    for (int t = 0; t < 7; t++) r2[t] = dt4[(size_t)k2[t] * 8 + l];
#pragma unroll
    for (int t = 0; t < 4; t++) roh[t] = dt4[(size_t)koh[t] * 8 + l];

#pragma unroll
    for (int t = 0; t < 4; t++) {
        int f = g + 8 * t;
        if (f < F_) {
            ushort4 o;
            o.x = f2b(roh[t].x * soh[t]); o.y = f2b(roh[t].y * soh[t]);
            o.z = f2b(roh[t].z * soh[t]); o.w = f2b(roh[t].w * soh[t]);
            *(ushort4*)(xrow + f * E_ + l * 4) = o;
        }
    }
    f32x4 a1 = {0.f,0.f,0.f,0.f}, a2 = {0.f,0.f,0.f,0.f};
#pragma unroll
    for (int t = 0; t < 7; t++) {
        a1.x = fmaf(r1[t].x, sc1[t], a1.x); a1.y = fmaf(r1[t].y, sc1[t], a1.y);
        a1.z = fmaf(r1[t].z, sc1[t], a1.z); a1.w = fmaf(r1[t].w, sc1[t], a1.w);
        a2.x = fmaf(r2[t].x, sc2[t], a2.x); a2.y = fmaf(r2[t].y, sc2[t], a2.y);
        a2.z = fmaf(r2[t].z, sc2[t], a2.z); a2.w = fmaf(r2[t].w, sc2[t], a2.w);
    }
#pragma unroll
    for (int m = 8; m < 64; m <<= 1) {
        a1.x += __shfl_xor(a1.x, m); a1.y += __shfl_xor(a1.y, m);
        a1.z += __shfl_xor(a1.z, m); a1.w += __shfl_xor(a1.w, m);
        a2.x += __shfl_xor(a2.x, m); a2.y += __shfl_xor(a2.y, m);
        a2.z += __shfl_xor(a2.z, m); a2.w += __shfl_xor(a2.w, m);
    }
    if (g == 0) {
        ushort4 o; o.x = f2b(a1.x); o.y = f2b(a1.y); o.z = f2b(a1.z); o.w = f2b(a1.w);
        *(ushort4*)(xrow + F_ * E_ + l * 4) = o;
    }
    if (g == 1) {
        ushort4 o; o.x = f2b(a2.x); o.y = f2b(a2.y); o.z = f2b(a2.z); o.w = f2b(a2.w);
        *(ushort4*)(xrow + F_ * E_ + E_ + l * 4) = o;
    }
    // ctns (cols 896..908) + explicit zero through col 959 [nt load]
    {
        float v = (lane < CT_) ? __builtin_nontemporal_load(ct + s * CT_ + lane) : 0.f;
        xrow[F_ * E_ + 2 * E_ + lane] = f2b(v);
    }
    // ---- wide part from preloaded registers (no input re-reads).
    // All 8 lanes of group g hold identical (idx, scale) sets; same-address
    // wtab loads broadcast-coalesce. Masked entries: wtab[0]*0 = 0.
    float aw = 0.f;
#pragma unroll
    for (int t = 0; t < 4; t++) aw = fmaf(wtab[koh[t]], soh[t], aw);
#pragma unroll
    for (int t = 0; t < 7; t++) {
        aw = fmaf(wtab[k1[t]], sc1[t], aw);
        aw = fmaf(wtab[k2[t]], sc2[t], aw);
    }
#pragma unroll
    for (int m = 8; m < 64; m <<= 1) aw += __shfl_xor(aw, m);   // sum the 8 groups
    if (lane == 0) wid[s] = (float)E_ * aw;
}

// ================= D1: gemm1  h1 = leaky(x0 @ W2^T + b2), 128x128 tile, BK=64 =================
__global__ __launch_bounds__(256) void gemm1_kernel(
    const __hip_bfloat16* __restrict__ A,
    const __hip_bfloat16* __restrict__ W,
    const float* __restrict__ bias,
    __hip_bfloat16* __restrict__ C)
{
    __shared__ __hip_bfloat16 As[2][128 * 32];   // two 32-col K-planes, 8KB each
    __shared__ __hip_bfloat16 Bs[2][128 * 32];

    const int xcd  = blockIdx.x & 7;
    const int loc  = blockIdx.x >> 3;            // 0..63
    const int bm   = xcd * 16 + (loc >> 2);      // 0..127
    const int bn   = loc & 3;                    // 0..3
    const int tid  = threadIdx.x;
    const int lane = tid & 63;
    const int w    = tid >> 6;
    const int wm   = w >> 1, wn = w & 1;

    f32x4 acc[4][4] = {};

    const int srow = lane >> 2;
    const int scol = (lane & 3) * 8;
    const __hip_bfloat16* Aw0 = A + ((size_t)bm * 128 + w * 32 + srow) * KP + scol;
    const __hip_bfloat16* Aw1 = Aw0 + (size_t)16 * KP;
    const __hip_bfloat16* Ww0 = W + ((size_t)bn * 128 + w * 32 + srow) * KP + scol;
    const __hip_bfloat16* Ww1 = Ww0 + (size_t)16 * KP;
    char* AsW = (char*)As + w * 2048;
    char* BsW = (char*)Bs + w * 2048;

    const int fr = lane & 15;
    const int kg = (lane >> 4) * 8;

    for (int k0 = 0; k0 < KP; k0 += 64) {
#pragma unroll
        for (int p = 0; p < 2; p++) {
            gld_lds16(Aw0 + k0 + p * 32, AsW + p * 8192);
            gld_lds16(Aw1 + k0 + p * 32, AsW + p * 8192 + 1024);
            gld_lds16(Ww0 + k0 + p * 32, BsW + p * 8192);
            gld_lds16(Ww1 + k0 + p * 32, BsW + p * 8192 + 1024);
        }
        __syncthreads();

#pragma unroll
        for (int p = 0; p < 2; p++) {
            bf16x8 af[4], bfv[4];
#pragma unroll
            for (int i = 0; i < 4; i++)
                af[i] = *(const bf16x8*)(As[p] + (wm * 64 + i * 16 + fr) * 32 + kg);
#pragma unroll
            for (int i = 0; i < 4; i++)
                bfv[i] = *(const bf16x8*)(Bs[p] + (wn * 64 + i * 16 + fr) * 32 + kg);
#pragma unroll
            for (int i = 0; i < 4; i++)
#pragma unroll
                for (int j = 0; j < 4; j++)
                    acc[i][j] = __builtin_amdgcn_mfma_f32_16x16x32_bf16(af[i], bfv[j], acc[i][j], 0, 0, 0);
        }
        __syncthreads();
    }

    float bv[4];
#pragma unroll
    for (int j = 0; j < 4; j++) bv[j] = bias[bn * 128 + wn * 64 + j * 16 + fr];
    const int crow0 = bm * 128 + wm * 64 + (lane >> 4) * 4;
    const int ccol0 = bn * 128 + wn * 64 + fr;
#pragma unroll
    for (int i = 0; i < 4; i++)
#pragma unroll
        for (int j = 0; j < 4; j++)
#pragma unroll
            for (int r = 0; r < 4; r++) {
                float v = acc[i][j][r] + bv[j];
                v = (v >= 0.f) ? v : 0.01f * v;
                C[(size_t)(crow0 + i * 16 + r) * D1_ + ccol0 + j * 16] = __float2bfloat16(v);
            }
}

// ================= D2: G2F  out = sigmoid(leaky(h1@W3^T+b3).w4 + b4 + wide), BK=64 =================
__global__ __launch_bounds__(256) void g2f_kernel(
    const __hip_bfloat16* __restrict__ h1b, const __hip_bfloat16* __restrict__ w3b,
    const float* __restrict__ b3, const float* __restrict__ w4,
    const float* __restrict__ b4, const float* __restrict__ wid,
    float* __restrict__ out)
{
    __shared__ __align__(16) __hip_bfloat16 As2[2][64 * 32];    // 4KB x2
    __shared__ __align__(16) __hip_bfloat16 Bs2[2][256 * 32];   // 16KB x2
    __shared__ float parts[256];

    const int tid  = threadIdx.x;
    const int lane = tid & 63;
    const int w    = tid >> 6;
    const int r0   = blockIdx.x * 64;

    f32x4 acc[4][4] = {};
    const int srow = lane >> 2;
    const int scol = (lane & 3) * 8;
    const int fr = lane & 15;
    const int kg = (lane >> 4) * 8;

    for (int k0 = 0; k0 < D1_; k0 += 64) {
#pragma unroll
        for (int p = 0; p < 2; p++) {
            gld_lds16(h1b + ((size_t)r0 + w * 16 + srow) * D1_ + k0 + p * 32 + scol,
                      (char*)As2 + p * 4096 + w * 1024);
#pragma unroll
            for (int rr = 0; rr < 4; rr++)
                gld_lds16(w3b + ((size_t)w * 64 + rr * 16 + srow) * D1_ + k0 + p * 32 + scol,
                          (char*)Bs2 + p * 16384 + w * 4096 + rr * 1024);
        }
        __syncthreads();
#pragma unroll
        for (int p = 0; p < 2; p++) {
            bf16x8 af[4], bfv[4];
#pragma unroll
            for (int i = 0; i < 4; i++)
                af[i] = *(const bf16x8*)(As2[p] + (i * 16 + fr) * 32 + kg);
#pragma unroll
            for (int j = 0; j < 4; j++)
                bfv[j] = *(const bf16x8*)(Bs2[p] + (w * 64 + j * 16 + fr) * 32 + kg);
#pragma unroll
            for (int i = 0; i < 4; i++)
#pragma unroll
                for (int j = 0; j < 4; j++)
                    acc[i][j] = __builtin_amdgcn_mfma_f32_16x16x32_bf16(af[i], bfv[j], acc[i][j], 0, 0, 0);
        }
        __syncthreads();
    }

    float p4[4][4];
#pragma unroll
    for (int i = 0; i < 4; i++)
#pragma unroll
        for (int r = 0; r < 4; r++) p4[i][r] = 0.f;
#pragma unroll
    for (int j = 0; j < 4; j++) {
        int n = w * 64 + j * 16 + fr;
        float bb = b3[n];
        float wv = w4[n];
#pragma unroll
        for (int i = 0; i < 4; i++)
#pragma unroll
            for (int r = 0; r < 4; r++) {
                float v = acc[i][j][r] + bb;
                v = (v >= 0.f) ? v : 0.01f * v;
                p4[i][r] = fmaf(v, wv, p4[i][r]);
            }
    }
#pragma unroll
    for (int m = 1; m < 16; m <<= 1)
#pragma unroll
        for (int i = 0; i < 4; i++)
#pragma unroll
            for (int r = 0; r < 4; r++) p4[i][r] += __shfl_xor(p4[i][r], m);
    if (fr == 0) {
        int kq = lane >> 4;
#pragma unroll
        for (int i = 0; i < 4; i++)
#pragma unroll
            for (int r = 0; r < 4; r++)
                parts[w * 64 + i * 16 + kq * 4 + r] = p4[i][r];
    }
    __syncthreads();
    if (tid < 64) {
        float x = parts[tid] + parts[64 + tid] + parts[128 + tid] + parts[192 + tid]
                + b4[0] + wid[r0 + tid];
        out[r0 + tid] = 1.f / (1.f + expf(-x));
    }
}

extern "C" void kernel_launch(void* const* d_in, const int* in_sizes, int n_in,
                              void* d_out, int out_size, void* d_ws, size_t ws_size,
                              hipStream_t stream) {
    const int*   oi  = (const int*)  d_in[0];
    const float* ox  = (const float*)d_in[1];
    const int*   i1  = (const int*)  d_in[2];
    const float* x1  = (const float*)d_in[3];
    const int*   i2  = (const int*)  d_in[4];
    const float* x2  = (const float*)d_in[5];
    const float* ct  = (const float*)d_in[6];
    const float* wt  = (const float*)d_in[7];
    const float* dt  = (const float*)d_in[8];
    const float* w2  = (const float*)d_in[9];
    const float* b2  = (const float*)d_in[10];
    const float* w3  = (const float*)d_in[11];
    const float* b3  = (const float*)d_in[12];
    const float* w4  = (const float*)d_in[13];
    const float* b4  = (const float*)d_in[14];
    float* out = (float*)d_out;

    char* ws = (char*)d_ws;
    __hip_bfloat16* x0b = (__hip_bfloat16*)(ws);                    // 16384*960*2  = 31,457,280
    __hip_bfloat16* h1b = (__hip_bfloat16*)(ws + 31457280);         // 16384*512*2  = 16,777,216
    float*          wid = (float*)         (ws + 48234496);         // 16384*4      =     65,536
    __hip_bfloat16* w2b = (__hip_bfloat16*)(ws + 48300032);         // 491520*2     =    983,040
    __hip_bfloat16* w3b = (__hip_bfloat16*)(ws + 49283072);         // 131072*2     =    262,144

    embed_cvt_kernel<<<NEMB + CVTB, 256, 0, stream>>>(
        oi, ox, i1, x1, i2, x2, ct, wt, dt, w2, w3, x0b, wid, w2b, w3b);
    gemm1_kernel<<<512, 256, 0, stream>>>(x0b, w2b, b2, h1b);
    g2f_kernel<<<256, 256, 0, stream>>>(h1b, w3b, b3, w4, b4, wid, out);
}